// Round 6
// baseline (394.287 us; speedup 1.0000x reference)
//
#include <hip/hip_runtime.h>
#include <math.h>

#define Bn 32
#define Pn 32768
#define On 32
#define TPB 256
#define PPT 4                 // priors per thread in matchB phase
#define BP  (TPB * PPT)       // priors per block = 1024
#define NCHUNK (Pn / BP)      // 32 chunk-blocks per batch

// d_ws layout:
// [0,     8192)  u64   bpm[Bn*On]   packed (iou_bits<<32 | (Pn-1-p)) per (b,o)
// [8192,  8320)  int   num_pos[Bn]
// [8320,  8324)  float loss_l_total
// [8324,  8328)  float ce_total
// [8328,  8332)  int   np_total
// [8332,  8336)  uint  tick (topk completion ticket)
// [8336,  8464)  uint  cnt[Bn] (per-batch phase-A completion ticket)
// [16384, 16384+4*Bn*Pn) float ce_mine[Bn*Pn]

__device__ __forceinline__ unsigned long long shfl_down_u64(unsigned long long v, int off) {
    unsigned lo = (unsigned)(v & 0xFFFFFFFFull);
    unsigned hi = (unsigned)(v >> 32);
    lo = __shfl_down(lo, off, 64);
    hi = __shfl_down(hi, off, 64);
    return ((unsigned long long)hi << 32) | lo;
}

// ---- fused matchAB: phase A (per-o argmax, register-resident priors,
// batched shuffle reduce, global atomicMax, per-batch ticket spin) then
// phase B (per-prior matching, loc loss, CE, ce_mine). grid (32,32) =
// 1024 blocks = exactly 4/CU x 256 CU with launch_bounds(256,4) -> all
// blocks co-resident -> spin is deadlock-free (R3-validated pattern).
__global__ __launch_bounds__(256, 4) void matchAB(const float* __restrict__ loc,
                                                  const float2* __restrict__ conf2,
                                                  const float4* __restrict__ priors,
                                                  const float* __restrict__ targets,
                                                  unsigned long long* __restrict__ bpm,
                                                  unsigned* __restrict__ cnt,
                                                  float* __restrict__ ce_mine,
                                                  int* __restrict__ num_pos,
                                                  float* __restrict__ loss_l_t,
                                                  float* __restrict__ ce_t,
                                                  int* __restrict__ np_tot) {
    int b = blockIdx.y;
    int base = blockIdx.x * BP;
    int tid = threadIdx.x;
    int lane = tid & 63, wv = tid >> 6;

    __shared__ float4 tb[On];
    __shared__ float  ta[On], lb[On];
    __shared__ int    forced[BP];    // truth index forcing this prior, else -1
    __shared__ float  sred[12];

#pragma unroll
    for (int j = 0; j < PPT; j++) forced[tid + 256 * j] = -1;
    if (tid < On) {
        const float* t = targets + ((size_t)b * On + tid) * 5;
        float x1 = t[0], y1 = t[1], x2 = t[2], y2 = t[3];
        tb[tid] = make_float4(x1, y1, x2, y2);
        ta[tid] = (x2 - x1) * (y2 - y1);
        lb[tid] = t[4];
    }
    __syncthreads();

    // ---------------- phase A: per-(b,o) argmax_p IoU ----------------
    // lane owns priors p = base + lane + 64*i (i ascending -> p ascending
    // within lane); each wave covers all 1024 block priors for 8 targets.
    {
        float4 pr[16];
#pragma unroll
        for (int i = 0; i < 16; i++) pr[i] = priors[base + lane + 64 * i];

        unsigned long long key[8];
#pragma unroll
        for (int t = 0; t < 8; t++) {
            int o = wv * 8 + t;
            float4 tt = tb[o];
            float  a  = ta[o];
            float bI = 0.f, bU = 1.f;
            int   bi = 0;
#pragma unroll
            for (int i = 0; i < 16; i++) {
                float px1 = pr[i].x - pr[i].z * 0.5f, py1 = pr[i].y - pr[i].w * 0.5f;
                float px2 = pr[i].x + pr[i].z * 0.5f, py2 = pr[i].y + pr[i].w * 0.5f;
                float ab  = (px2 - px1) * (py2 - py1);
                float ix1 = fmaxf(tt.x, px1), iy1 = fmaxf(tt.y, py1);
                float ix2 = fminf(tt.z, px2), iy2 = fminf(tt.w, py2);
                float iw = fmaxf(ix2 - ix1, 0.f), ih = fmaxf(iy2 - iy1, 0.f);
                float I = iw * ih;
                float U = a + ab - I;
                if (I * bU > bI * U) { bI = I; bU = U; bi = i; }
            }
            int p = base + lane + 64 * bi;
            float iou = bI / bU;             // IEEE divide: reference key rounding
            key[t] = ((unsigned long long)__float_as_uint(iou) << 32)
                   | (unsigned)(Pn - 1 - p);
        }
        // interleaved 6-level wave max-reduce of all 8 keys at once
#pragma unroll
        for (int off = 32; off > 0; off >>= 1) {
            unsigned long long other[8];
#pragma unroll
            for (int t = 0; t < 8; t++) other[t] = shfl_down_u64(key[t], off);
#pragma unroll
            for (int t = 0; t < 8; t++) if (other[t] > key[t]) key[t] = other[t];
        }
        if (lane == 0) {
#pragma unroll
            for (int t = 0; t < 8; t++)
                atomicMax(&bpm[b * On + wv * 8 + t], key[t]);
        }
    }

    // conf2 prefetch: issued here so HBM latency drains under fence+spin
    float2 cc[PPT];
#pragma unroll
    for (int j = 0; j < PPT; j++) cc[j] = conf2[(size_t)b * Pn + base + tid + 256 * j];

    __threadfence();            // drain this wave's atomics (device-visible)
    __syncthreads();            // all 4 waves' contributions complete

    // per-batch ticket: wait for all NCHUNK sibling chunk-blocks
    if (tid == 0) {
        atomicAdd(&cnt[b], 1u);
        while (atomicAdd(&cnt[b], 0u) < (unsigned)NCHUNK) {
            __builtin_amdgcn_s_sleep(2);
        }
    }
    __syncthreads();

    int sp = -1;
    if (tid < On)
        sp = Pn - 1 - (int)(atomicMax(&bpm[b * On + tid], 0ull) & 0xFFFFFFFFull);
    if (tid < On && sp >= base && sp < base + BP)
        atomicMax(&forced[sp - base], tid);   // duplicate bpi: max o == numpy last-write
    __syncthreads();

    // ---------------- phase B (verified matchB body) ----------------
    float px1[PPT], py1[PPT], px2[PPT], py2[PPT], ab[PPT], pcx[PPT], pcy[PPT], pw[PPT], ph[PPT];
#pragma unroll
    for (int j = 0; j < PPT; j++) {
        float4 pr = priors[base + tid + 256 * j];
        pcx[j] = pr.x; pcy[j] = pr.y; pw[j] = pr.z; ph[j] = pr.w;
        px1[j] = pr.x - pr.z * 0.5f; py1[j] = pr.y - pr.w * 0.5f;
        px2[j] = pr.x + pr.z * 0.5f; py2[j] = pr.y + pr.w * 0.5f;
        ab[j]  = (px2[j] - px1[j]) * (py2[j] - py1[j]);
    }

    // two independent 16-long chains per prior (h = o/16), merged after.
    float bIc[PPT][2], bUc[PPT][2];
    int   bxc[PPT][2];
#pragma unroll
    for (int j = 0; j < PPT; j++)
#pragma unroll
        for (int h = 0; h < 2; h++) { bIc[j][h] = 0.f; bUc[j][h] = 1.f; bxc[j][h] = h * 16; }

#pragma unroll 2
    for (int o16 = 0; o16 < 16; o16++) {
#pragma unroll
        for (int h = 0; h < 2; h++) {
            int o = h * 16 + o16;
            float4 tt = tb[o];
            float  a  = ta[o];
#pragma unroll
            for (int j = 0; j < PPT; j++) {
                float ix1 = fmaxf(tt.x, px1[j]), iy1 = fmaxf(tt.y, py1[j]);
                float ix2 = fminf(tt.z, px2[j]), iy2 = fminf(tt.w, py2[j]);
                float iw = fmaxf(ix2 - ix1, 0.f), ih = fmaxf(iy2 - iy1, 0.f);
                float I = iw * ih;
                float U = a + ab[j] - I;
                if (I * bUc[j][h] > bIc[j][h] * U) { bIc[j][h] = I; bUc[j][h] = U; bxc[j][h] = o; }
            }
        }
    }
    // merge: chain1 wins only if strictly greater -> earliest-o tie semantics kept
    float bI[PPT], bU[PPT];
    int   bx[PPT];
#pragma unroll
    for (int j = 0; j < PPT; j++) {
        bI[j] = bIc[j][0]; bU[j] = bUc[j][0]; bx[j] = bxc[j][0];
        if (bIc[j][1] * bU[j] > bI[j] * bUc[j][1]) { bI[j] = bIc[j][1]; bU[j] = bUc[j][1]; bx[j] = bxc[j][1]; }
    }

    float ll_s = 0.f, pce_s = 0.f, cnt_s = 0.f;
#pragma unroll
    for (int j = 0; j < PPT; j++) {
        int p = base + tid + 256 * j;
        int fo = forced[tid + 256 * j];
        int bidx = (fo >= 0) ? fo : bx[j];
        int cf;
        if (fo >= 0)                      cf = (int)lb[bidx];
        else if (bI[j] >= 0.5f * bU[j])   cf = (int)lb[bidx];
        else                              cf = 0;
        bool pos = cf > 0;

        if (pos) {
            float4 tt = tb[bidx];
            float g0 = ((tt.x + tt.z) * 0.5f - pcx[j]) / (0.1f * pw[j]);
            float g1 = ((tt.y + tt.w) * 0.5f - pcy[j]) / (0.1f * ph[j]);
            float g2 = __logf((tt.z - tt.x) / pw[j]) * 5.0f;
            float g3 = __logf((tt.w - tt.y) / ph[j]) * 5.0f;
            const float* lp = loc + ((size_t)b * Pn + p) * 3;
            float q0 = lp[0], q1 = lp[1], q2 = lp[2];
            float dd[4] = { q0 - g0, q1 - g1, q2 - g2, q2 - g3 };
#pragma unroll
            for (int i = 0; i < 4; i++) {
                float ad = fabsf(dd[i]);
                ll_s += (ad < 1.f) ? 0.5f * dd[i] * dd[i] : (ad - 0.5f);
            }
            cnt_s += 1.f;
        }

        float m = fmaxf(cc[j].x, cc[j].y);
        float lse = m + __logf(__expf(cc[j].x - m) + __expf(cc[j].y - m));
        float ce = lse - (cf ? cc[j].y : cc[j].x);     // >= 0
        if (pos) { pce_s += ce; ce = 0.f; }
        ce_mine[(size_t)b * Pn + p] = fmaxf(ce, 0.f);
    }

    // fused 3-value block reduce
#pragma unroll
    for (int off = 32; off > 0; off >>= 1) {
        ll_s  += __shfl_down(ll_s,  off, 64);
        pce_s += __shfl_down(pce_s, off, 64);
        cnt_s += __shfl_down(cnt_s, off, 64);
    }
    if (lane == 0) { sred[wv * 3] = ll_s; sred[wv * 3 + 1] = pce_s; sred[wv * 3 + 2] = cnt_s; }
    __syncthreads();
    if (tid == 0) {
        float llr = 0, pcer = 0, cntr = 0;
        for (int w = 0; w < 4; w++) { llr += sred[w*3]; pcer += sred[w*3+1]; cntr += sred[w*3+2]; }
        if (llr != 0.f)  atomicAdd(loss_l_t, llr);
        if (pcer != 0.f) atomicAdd(ce_t, pcer);
        int c = (int)cntr;
        if (c) { atomicAdd(&num_pos[b], c); atomicAdd(np_tot, c); }
    }
}

// ---- Phase C: exact top-k sum via 3-round radix histogram select ----
// (unchanged control from round 5)
__global__ __launch_bounds__(1024) void topk(const float* __restrict__ ce_mine,
                                             const int* __restrict__ num_pos,
                                             float* __restrict__ ce_t,
                                             const float* __restrict__ loss_l_t,
                                             const int* __restrict__ np_tot,
                                             unsigned* __restrict__ tick,
                                             float* __restrict__ out) {
    int b = blockIdx.x, tid = threadIdx.x;
    const float4* v4 = (const float4*)(ce_mine + (size_t)b * Pn);
    float4 r[8];
#pragma unroll
    for (int i = 0; i < 8; i++) r[i] = v4[i * 1024 + tid];

    int k = 3 * num_pos[b];
    if (k > Pn - 1) k = Pn - 1;

    __shared__ int hist[8192];                // 4 sub-hists x 2048 bins (32KB)
    __shared__ unsigned s_lo;
    __shared__ int s_ab;
    __shared__ float ssum[16];
    __shared__ int   scnt[16];

    int lane = tid & 63, wv = tid >> 6;

    if (k > 0) {                              // uniform across block
        unsigned LO = 0u;
        int AB = 0;                           // count(u >= bracket top)

        const int SH[3] = {22, 11, 0};
        const int NB[3] = {512, 2048, 2048};

#pragma unroll
        for (int rd = 0; rd < 3; rd++) {
            int shift = SH[rd], nb = NB[rd];
#pragma unroll
            for (int i = 0; i < 8; i++) hist[tid + 1024 * i] = 0;
            __syncthreads();
            int* myh = hist + ((wv >> 2) << 11);   // 4-way sub-hist
#pragma unroll
            for (int i = 0; i < 8; i++) {
                float4 rv = r[i];
                float vals[4] = {rv.x, rv.y, rv.z, rv.w};
#pragma unroll
                for (int q = 0; q < 4; q++) {
                    unsigned u = __float_as_uint(vals[q]);
                    unsigned bin = (u - LO) >> shift;        // underflow -> huge -> skipped
                    if (bin < (unsigned)nb) atomicAdd(&myh[bin], 1);
                }
            }
            __syncthreads();
            if (wv == 0) {
                int bpl = nb >> 6;            // bins per lane: 8 or 32
                int bb = lane * bpl;
                int lsum = 0;
                for (int q = 0; q < bpl; q++) {
                    int bin = bb + q;
                    lsum += hist[bin] + hist[2048 + bin] + hist[4096 + bin] + hist[6144 + bin];
                }
                // inclusive suffix-scan over lanes: suf = count(bins >= bb)
                int suf = lsum;
#pragma unroll
                for (int off = 1; off < 64; off <<= 1) {
                    int o = __shfl(suf, (lane + off) & 63, 64);
                    suf += ((lane + off) < 64) ? o : 0;
                }
                int kk = k - AB;              // >= 1 by invariant
                if (suf >= kk && (suf - lsum) < kk) {   // crossing lane (unique)
                    int acc = suf - lsum;     // count(bins >= bb+bpl)
                    for (int q = bpl - 1; q >= 0; q--) {
                        int bin = bb + q;
                        int hc = hist[bin] + hist[2048 + bin] + hist[4096 + bin] + hist[6144 + bin];
                        acc += hc;            // = count(bins >= bb+q)
                        if (acc >= kk) {
                            s_lo = LO + ((unsigned)bin << shift);
                            s_ab = AB + (acc - hc);
                            break;
                        }
                    }
                }
            }
            __syncthreads();
            LO = s_lo; AB = s_ab;
        }
        // final bracket width 1: tau bits == LO; count(> tau) = AB < k <= count(>= tau)
        float tau = __uint_as_float(LO);
        float s = 0.f; int c = 0;
#pragma unroll
        for (int i = 0; i < 8; i++) {
            if (r[i].x > tau) { s += r[i].x; c++; }
            if (r[i].y > tau) { s += r[i].y; c++; }
            if (r[i].z > tau) { s += r[i].z; c++; }
            if (r[i].w > tau) { s += r[i].w; c++; }
        }
#pragma unroll
        for (int off = 32; off > 0; off >>= 1) {
            s += __shfl_down(s, off, 64);
            c += __shfl_down(c, off, 64);
        }
        if (lane == 0) { ssum[wv] = s; scnt[wv] = c; }
        __syncthreads();
        if (tid == 0) {
            float st = 0.f; int ct = 0;
            for (int w = 0; w < 16; w++) { st += ssum[w]; ct += scnt[w]; }
            atomicAdd(ce_t, st + (float)(k - ct) * tau);   // ties at tau, tie-agnostic exact
        }
    }

    // ticket: last block finalizes (device-scope atomics; adds happen-before ticket)
    if (tid == 0) {
        __threadfence();
        unsigned done = atomicAdd(tick, 1u);
        if (done == (unsigned)(Bn - 1)) {
            float N  = (float)atomicAdd((int*)np_tot, 0);
            float ll = atomicAdd((float*)loss_l_t, 0.f);
            float ce = atomicAdd(ce_t, 0.f);
            out[0] = ll / N;
            out[1] = ce / N;
        }
    }
}

extern "C" void kernel_launch(void* const* d_in, const int* in_sizes, int n_in,
                              void* d_out, int out_size, void* d_ws, size_t ws_size,
                              hipStream_t stream) {
    const float* loc     = (const float*)d_in[0];  // (B,P,3)
    const float* conf    = (const float*)d_in[1];  // (B,P,2)
    const float* priors  = (const float*)d_in[2];  // (P,4)
    const float* targets = (const float*)d_in[3];  // (B,O,5)
    float* out = (float*)d_out;

    char* ws = (char*)d_ws;
    unsigned long long* bpm = (unsigned long long*)ws;
    int*   num_pos  = (int*)(ws + 8192);
    float* loss_l_t = (float*)(ws + 8320);
    float* ce_t     = (float*)(ws + 8324);
    int*   np_tot   = (int*)(ws + 8328);
    unsigned* tick  = (unsigned*)(ws + 8332);
    unsigned* cnt   = (unsigned*)(ws + 8336);
    float* ce_mine  = (float*)(ws + 16384);

    hipMemsetAsync(ws, 0, 16384, stream);

    hipLaunchKernelGGL(matchAB, dim3(NCHUNK, Bn), dim3(256), 0, stream,
                       loc, (const float2*)conf, (const float4*)priors, targets,
                       bpm, cnt, ce_mine, num_pos, loss_l_t, ce_t, np_tot);
    hipLaunchKernelGGL(topk, dim3(Bn), dim3(1024), 0, stream,
                       ce_mine, num_pos, ce_t, loss_l_t, np_tot, tick, out);
}

// Round 7
// 260.248 us; speedup vs baseline: 1.5150x; 1.5150x over previous
//
#include <hip/hip_runtime.h>
#include <math.h>

#define Bn 32
#define Pn 32768
#define On 32
#define TPB 256
#define PPT 4                 // priors per thread in phase B
#define BP  (TPB * PPT)       // priors per block = 1024
#define NCHUNK (Pn / BP)      // 32 chunk-blocks per batch

// d_ws layout:
// [0,     8192)  u64   bpm[Bn*On]   packed (iou_bits<<32 | (Pn-1-p)) per (b,o)
// [8192,  8320)  int   num_pos[Bn]
// [8320,  8324)  float loss_l_total
// [8324,  8328)  float ce_total
// [8328,  8332)  int   np_total
// [8332,  8336)  uint  tick (topk completion ticket)
// [8336,  8464)  uint  cnt[Bn] (per-batch phase-A completion ticket)
// [16384, 16384+4*Bn*Pn) float ce_mine[Bn*Pn]

__device__ __forceinline__ unsigned long long shfl_down_u64(unsigned long long v, int off) {
    unsigned lo = (unsigned)(v & 0xFFFFFFFFull);
    unsigned hi = (unsigned)(v >> 32);
    lo = __shfl_down(lo, off, 64);
    hi = __shfl_down(hi, off, 64);
    return ((unsigned long long)hi << 32) | lo;
}

// ---- fused matchAB v3 ----
// Phase A: lane owns 16 priors (corner/area precomputed in regs); each wave
// covers 8 targets x 1024 priors; batched 6-level shuffle key-reduce; lane 0
// does 8 global atomicMax. NO LDS atomics (r3 defect), NO threadfence (r6
// defect: agent fence = per-block L2 writeback -> 148MB write storm).
// Ordering: __syncthreads drains the bpm atomics (vmcnt(0)) before the
// ticket increment — the fence-free pattern round 3 validated (absmax 0).
// Phase B: verified round-2 matchB body, verbatim.
// grid (32,32)=1024 blocks; launch_bounds(256,4) forces VGPR<=128 -> 4
// blocks/CU co-resident by construction -> ticket spin is deadlock-free.
__global__ __launch_bounds__(256, 4) void matchAB(const float* __restrict__ loc,
                                                  const float2* __restrict__ conf2,
                                                  const float4* __restrict__ priors,
                                                  const float* __restrict__ targets,
                                                  unsigned long long* __restrict__ bpm,
                                                  unsigned* __restrict__ cnt,
                                                  float* __restrict__ ce_mine,
                                                  int* __restrict__ num_pos,
                                                  float* __restrict__ loss_l_t,
                                                  float* __restrict__ ce_t,
                                                  int* __restrict__ np_tot) {
    int b = blockIdx.y;
    int base = blockIdx.x * BP;
    int tid = threadIdx.x;
    int lane = tid & 63, wv = tid >> 6;

    __shared__ float4 tb[On];
    __shared__ float  ta[On], lb[On];
    __shared__ int    forced[BP];    // truth index forcing this prior, else -1
    __shared__ float  sred[12];

#pragma unroll
    for (int j = 0; j < PPT; j++) forced[tid + 256 * j] = -1;
    if (tid < On) {
        const float* t = targets + ((size_t)b * On + tid) * 5;
        float x1 = t[0], y1 = t[1], x2 = t[2], y2 = t[3];
        tb[tid] = make_float4(x1, y1, x2, y2);
        ta[tid] = (x2 - x1) * (y2 - y1);
        lb[tid] = t[4];
    }
    __syncthreads();

    // ---------------- phase A: per-(b,o) argmax_p IoU ----------------
    // lane owns priors p = base + lane + 64*i (i ascending -> p ascending)
    {
        float ax1[16], ay1[16], ax2[16], ay2[16], aa[16];
#pragma unroll
        for (int i = 0; i < 16; i++) {
            float4 pr = priors[base + lane + 64 * i];
            ax1[i] = pr.x - pr.z * 0.5f; ay1[i] = pr.y - pr.w * 0.5f;
            ax2[i] = pr.x + pr.z * 0.5f; ay2[i] = pr.y + pr.w * 0.5f;
            aa[i]  = (ax2[i] - ax1[i]) * (ay2[i] - ay1[i]);
        }

        unsigned long long key[8];
#pragma unroll
        for (int t = 0; t < 8; t++) {
            int o = wv * 8 + t;
            float4 tt = tb[o];
            float  a  = ta[o];
            float bI = 0.f, bU = 1.f;
            int   bi = 0;
#pragma unroll
            for (int i = 0; i < 16; i++) {
                float ix1 = fmaxf(tt.x, ax1[i]), iy1 = fmaxf(tt.y, ay1[i]);
                float ix2 = fminf(tt.z, ax2[i]), iy2 = fminf(tt.w, ay2[i]);
                float iw = fmaxf(ix2 - ix1, 0.f), ih = fmaxf(iy2 - iy1, 0.f);
                float I = iw * ih;
                float U = a + aa[i] - I;
                if (I * bU > bI * U) { bI = I; bU = U; bi = i; }
            }
            int p = base + lane + 64 * bi;
            float iou = bI / bU;             // IEEE divide: reference key rounding
            key[t] = ((unsigned long long)__float_as_uint(iou) << 32)
                   | (unsigned)(Pn - 1 - p);
        }
        // interleaved 6-level wave max-reduce of all 8 keys at once
#pragma unroll
        for (int off = 32; off > 0; off >>= 1) {
            unsigned long long other[8];
#pragma unroll
            for (int t = 0; t < 8; t++) other[t] = shfl_down_u64(key[t], off);
#pragma unroll
            for (int t = 0; t < 8; t++) if (other[t] > key[t]) key[t] = other[t];
        }
        if (lane == 0) {
#pragma unroll
            for (int t = 0; t < 8; t++)
                atomicMax(&bpm[b * On + wv * 8 + t], key[t]);
        }
    }

    // conf2 prefetch: HBM latency drains under barrier + spin
    float2 cc[PPT];
#pragma unroll
    for (int j = 0; j < PPT; j++) cc[j] = conf2[(size_t)b * Pn + base + tid + 256 * j];

    __syncthreads();            // vmcnt(0) drain: bpm atomics performed

    // per-batch ticket: wait for all NCHUNK sibling chunk-blocks.
    // RMW-only communication (atomics are coherent at device scope);
    // s_sleep(16) ~1k-cycle backoff keeps poll traffic negligible.
    if (tid == 0) {
        atomicAdd(&cnt[b], 1u);
        while (atomicAdd(&cnt[b], 0u) < (unsigned)NCHUNK) {
            __builtin_amdgcn_s_sleep(16);
        }
    }
    __syncthreads();

    int sp = -1;
    if (tid < On)
        sp = Pn - 1 - (int)(atomicMax(&bpm[b * On + tid], 0ull) & 0xFFFFFFFFull);
    if (tid < On && sp >= base && sp < base + BP)
        atomicMax(&forced[sp - base], tid);   // duplicate bpi: max o == numpy last-write
    __syncthreads();

    // ---------------- phase B (verified matchB body) ----------------
    float px1[PPT], py1[PPT], px2[PPT], py2[PPT], ab[PPT], pcx[PPT], pcy[PPT], pw[PPT], ph[PPT];
#pragma unroll
    for (int j = 0; j < PPT; j++) {
        float4 pr = priors[base + tid + 256 * j];
        pcx[j] = pr.x; pcy[j] = pr.y; pw[j] = pr.z; ph[j] = pr.w;
        px1[j] = pr.x - pr.z * 0.5f; py1[j] = pr.y - pr.w * 0.5f;
        px2[j] = pr.x + pr.z * 0.5f; py2[j] = pr.y + pr.w * 0.5f;
        ab[j]  = (px2[j] - px1[j]) * (py2[j] - py1[j]);
    }

    // two independent 16-long chains per prior (h = o/16), merged after.
    float bIc[PPT][2], bUc[PPT][2];
    int   bxc[PPT][2];
#pragma unroll
    for (int j = 0; j < PPT; j++)
#pragma unroll
        for (int h = 0; h < 2; h++) { bIc[j][h] = 0.f; bUc[j][h] = 1.f; bxc[j][h] = h * 16; }

#pragma unroll 2
    for (int o16 = 0; o16 < 16; o16++) {
#pragma unroll
        for (int h = 0; h < 2; h++) {
            int o = h * 16 + o16;
            float4 tt = tb[o];
            float  a  = ta[o];
#pragma unroll
            for (int j = 0; j < PPT; j++) {
                float ix1 = fmaxf(tt.x, px1[j]), iy1 = fmaxf(tt.y, py1[j]);
                float ix2 = fminf(tt.z, px2[j]), iy2 = fminf(tt.w, py2[j]);
                float iw = fmaxf(ix2 - ix1, 0.f), ih = fmaxf(iy2 - iy1, 0.f);
                float I = iw * ih;
                float U = a + ab[j] - I;
                if (I * bUc[j][h] > bIc[j][h] * U) { bIc[j][h] = I; bUc[j][h] = U; bxc[j][h] = o; }
            }
        }
    }
    // merge: chain1 wins only if strictly greater -> earliest-o tie semantics kept
    float bI[PPT], bU[PPT];
    int   bx[PPT];
#pragma unroll
    for (int j = 0; j < PPT; j++) {
        bI[j] = bIc[j][0]; bU[j] = bUc[j][0]; bx[j] = bxc[j][0];
        if (bIc[j][1] * bU[j] > bI[j] * bUc[j][1]) { bI[j] = bIc[j][1]; bU[j] = bUc[j][1]; bx[j] = bxc[j][1]; }
    }

    float ll_s = 0.f, pce_s = 0.f, cnt_s = 0.f;
#pragma unroll
    for (int j = 0; j < PPT; j++) {
        int p = base + tid + 256 * j;
        int fo = forced[tid + 256 * j];
        int bidx = (fo >= 0) ? fo : bx[j];
        int cf;
        if (fo >= 0)                      cf = (int)lb[bidx];
        else if (bI[j] >= 0.5f * bU[j])   cf = (int)lb[bidx];
        else                              cf = 0;
        bool pos = cf > 0;

        if (pos) {
            float4 tt = tb[bidx];
            float g0 = ((tt.x + tt.z) * 0.5f - pcx[j]) / (0.1f * pw[j]);
            float g1 = ((tt.y + tt.w) * 0.5f - pcy[j]) / (0.1f * ph[j]);
            float g2 = __logf((tt.z - tt.x) / pw[j]) * 5.0f;
            float g3 = __logf((tt.w - tt.y) / ph[j]) * 5.0f;
            const float* lp = loc + ((size_t)b * Pn + p) * 3;
            float q0 = lp[0], q1 = lp[1], q2 = lp[2];
            float dd[4] = { q0 - g0, q1 - g1, q2 - g2, q2 - g3 };
#pragma unroll
            for (int i = 0; i < 4; i++) {
                float ad = fabsf(dd[i]);
                ll_s += (ad < 1.f) ? 0.5f * dd[i] * dd[i] : (ad - 0.5f);
            }
            cnt_s += 1.f;
        }

        float m = fmaxf(cc[j].x, cc[j].y);
        float lse = m + __logf(__expf(cc[j].x - m) + __expf(cc[j].y - m));
        float ce = lse - (cf ? cc[j].y : cc[j].x);     // >= 0
        if (pos) { pce_s += ce; ce = 0.f; }
        ce_mine[(size_t)b * Pn + p] = fmaxf(ce, 0.f);
    }

    // fused 3-value block reduce
#pragma unroll
    for (int off = 32; off > 0; off >>= 1) {
        ll_s  += __shfl_down(ll_s,  off, 64);
        pce_s += __shfl_down(pce_s, off, 64);
        cnt_s += __shfl_down(cnt_s, off, 64);
    }
    if (lane == 0) { sred[wv * 3] = ll_s; sred[wv * 3 + 1] = pce_s; sred[wv * 3 + 2] = cnt_s; }
    __syncthreads();
    if (tid == 0) {
        float llr = 0, pcer = 0, cntr = 0;
        for (int w = 0; w < 4; w++) { llr += sred[w*3]; pcer += sred[w*3+1]; cntr += sred[w*3+2]; }
        if (llr != 0.f)  atomicAdd(loss_l_t, llr);
        if (pcer != 0.f) atomicAdd(ce_t, pcer);
        int c = (int)cntr;
        if (c) { atomicAdd(&num_pos[b], c); atomicAdd(np_tot, c); }
    }
}

// ---- Phase C: exact top-k sum via 3-round radix histogram select ----
// (unchanged control from round 5)
__global__ __launch_bounds__(1024) void topk(const float* __restrict__ ce_mine,
                                             const int* __restrict__ num_pos,
                                             float* __restrict__ ce_t,
                                             const float* __restrict__ loss_l_t,
                                             const int* __restrict__ np_tot,
                                             unsigned* __restrict__ tick,
                                             float* __restrict__ out) {
    int b = blockIdx.x, tid = threadIdx.x;
    const float4* v4 = (const float4*)(ce_mine + (size_t)b * Pn);
    float4 r[8];
#pragma unroll
    for (int i = 0; i < 8; i++) r[i] = v4[i * 1024 + tid];

    int k = 3 * num_pos[b];
    if (k > Pn - 1) k = Pn - 1;

    __shared__ int hist[8192];                // 4 sub-hists x 2048 bins (32KB)
    __shared__ unsigned s_lo;
    __shared__ int s_ab;
    __shared__ float ssum[16];
    __shared__ int   scnt[16];

    int lane = tid & 63, wv = tid >> 6;

    if (k > 0) {                              // uniform across block
        unsigned LO = 0u;
        int AB = 0;                           // count(u >= bracket top)

        const int SH[3] = {22, 11, 0};
        const int NB[3] = {512, 2048, 2048};

#pragma unroll
        for (int rd = 0; rd < 3; rd++) {
            int shift = SH[rd], nb = NB[rd];
#pragma unroll
            for (int i = 0; i < 8; i++) hist[tid + 1024 * i] = 0;
            __syncthreads();
            int* myh = hist + ((wv >> 2) << 11);   // 4-way sub-hist
#pragma unroll
            for (int i = 0; i < 8; i++) {
                float4 rv = r[i];
                float vals[4] = {rv.x, rv.y, rv.z, rv.w};
#pragma unroll
                for (int q = 0; q < 4; q++) {
                    unsigned u = __float_as_uint(vals[q]);
                    unsigned bin = (u - LO) >> shift;        // underflow -> huge -> skipped
                    if (bin < (unsigned)nb) atomicAdd(&myh[bin], 1);
                }
            }
            __syncthreads();
            if (wv == 0) {
                int bpl = nb >> 6;            // bins per lane: 8 or 32
                int bb = lane * bpl;
                int lsum = 0;
                for (int q = 0; q < bpl; q++) {
                    int bin = bb + q;
                    lsum += hist[bin] + hist[2048 + bin] + hist[4096 + bin] + hist[6144 + bin];
                }
                // inclusive suffix-scan over lanes: suf = count(bins >= bb)
                int suf = lsum;
#pragma unroll
                for (int off = 1; off < 64; off <<= 1) {
                    int o = __shfl(suf, (lane + off) & 63, 64);
                    suf += ((lane + off) < 64) ? o : 0;
                }
                int kk = k - AB;              // >= 1 by invariant
                if (suf >= kk && (suf - lsum) < kk) {   // crossing lane (unique)
                    int acc = suf - lsum;     // count(bins >= bb+bpl)
                    for (int q = bpl - 1; q >= 0; q--) {
                        int bin = bb + q;
                        int hc = hist[bin] + hist[2048 + bin] + hist[4096 + bin] + hist[6144 + bin];
                        acc += hc;            // = count(bins >= bb+q)
                        if (acc >= kk) {
                            s_lo = LO + ((unsigned)bin << shift);
                            s_ab = AB + (acc - hc);
                            break;
                        }
                    }
                }
            }
            __syncthreads();
            LO = s_lo; AB = s_ab;
        }
        // final bracket width 1: tau bits == LO; count(> tau) = AB < k <= count(>= tau)
        float tau = __uint_as_float(LO);
        float s = 0.f; int c = 0;
#pragma unroll
        for (int i = 0; i < 8; i++) {
            if (r[i].x > tau) { s += r[i].x; c++; }
            if (r[i].y > tau) { s += r[i].y; c++; }
            if (r[i].z > tau) { s += r[i].z; c++; }
            if (r[i].w > tau) { s += r[i].w; c++; }
        }
#pragma unroll
        for (int off = 32; off > 0; off >>= 1) {
            s += __shfl_down(s, off, 64);
            c += __shfl_down(c, off, 64);
        }
        if (lane == 0) { ssum[wv] = s; scnt[wv] = c; }
        __syncthreads();
        if (tid == 0) {
            float st = 0.f; int ct = 0;
            for (int w = 0; w < 16; w++) { st += ssum[w]; ct += scnt[w]; }
            atomicAdd(ce_t, st + (float)(k - ct) * tau);   // ties at tau, tie-agnostic exact
        }
    }

    // ticket: last block finalizes (device-scope atomics; adds happen-before ticket)
    if (tid == 0) {
        __threadfence();
        unsigned done = atomicAdd(tick, 1u);
        if (done == (unsigned)(Bn - 1)) {
            float N  = (float)atomicAdd((int*)np_tot, 0);
            float ll = atomicAdd((float*)loss_l_t, 0.f);
            float ce = atomicAdd(ce_t, 0.f);
            out[0] = ll / N;
            out[1] = ce / N;
        }
    }
}

extern "C" void kernel_launch(void* const* d_in, const int* in_sizes, int n_in,
                              void* d_out, int out_size, void* d_ws, size_t ws_size,
                              hipStream_t stream) {
    const float* loc     = (const float*)d_in[0];  // (B,P,3)
    const float* conf    = (const float*)d_in[1];  // (B,P,2)
    const float* priors  = (const float*)d_in[2];  // (P,4)
    const float* targets = (const float*)d_in[3];  // (B,O,5)
    float* out = (float*)d_out;

    char* ws = (char*)d_ws;
    unsigned long long* bpm = (unsigned long long*)ws;
    int*   num_pos  = (int*)(ws + 8192);
    float* loss_l_t = (float*)(ws + 8320);
    float* ce_t     = (float*)(ws + 8324);
    int*   np_tot   = (int*)(ws + 8328);
    unsigned* tick  = (unsigned*)(ws + 8332);
    unsigned* cnt   = (unsigned*)(ws + 8336);
    float* ce_mine  = (float*)(ws + 16384);

    hipMemsetAsync(ws, 0, 16384, stream);

    hipLaunchKernelGGL(matchAB, dim3(NCHUNK, Bn), dim3(256), 0, stream,
                       loc, (const float2*)conf, (const float4*)priors, targets,
                       bpm, cnt, ce_mine, num_pos, loss_l_t, ce_t, np_tot);
    hipLaunchKernelGGL(topk, dim3(Bn), dim3(1024), 0, stream,
                       ce_mine, num_pos, ce_t, loss_l_t, np_tot, tick, out);
}

// Round 8
// 187.801 us; speedup vs baseline: 2.0995x; 1.3858x over previous
//
#include <hip/hip_runtime.h>
#include <math.h>

#define Bn 32
#define Pn 32768
#define On 32
#define TPB 256
#define PPT 4                 // priors per thread in phase B
#define BP  (TPB * PPT)       // priors per block = 1024
#define NCHUNK (Pn / BP)      // 32 chunk-blocks per batch

// d_ws layout:
// [0,     8192)  u64   bpm[Bn*On]   packed (iou_bits<<32 | (Pn-1-p)) per (b,o)
// [8192,  8320)  int   num_pos[Bn]
// [8320,  8324)  float loss_l_total
// [8324,  8328)  float ce_total
// [8328,  8332)  int   np_total
// [8332,  8336)  uint  tick (topk completion ticket)
// [8336,  8464)  uint  cnt[Bn] (per-batch phase-A completion ticket)
// [16384, 16384+4*Bn*Pn) float ce_mine[Bn*Pn]

__device__ __forceinline__ unsigned long long shfl_down_u64(unsigned long long v, int off) {
    unsigned lo = (unsigned)(v & 0xFFFFFFFFull);
    unsigned hi = (unsigned)(v >> 32);
    lo = __shfl_down(lo, off, 64);
    hi = __shfl_down(hi, off, 64);
    return ((unsigned long long)hi << 32) | lo;
}

// ---- fused matchAB v4 ----
// Phase A: lane owns 16 priors processed in TWO SEQUENTIAL HALVES of 8
// (corners/area recomputed per half) so peak live registers ~85 fits the
// launch_bounds(256,4) 128-VGPR cap WITHOUT SPILL (r7 defect: 16-wide
// register arrays spilled to scratch -> 139MB HBM write storm).
// No LDS atomics (r3 defect), no threadfence (r6 defect).
// Ordering: __syncthreads drains the bpm atomics before ticket increment.
// Phase B: verified round-2 matchB body, verbatim.
// grid (32,32)=1024 blocks; launch_bounds(256,4) forces VGPR<=128 -> 4
// blocks/CU co-resident by construction -> ticket spin is deadlock-free.
__global__ __launch_bounds__(256, 4) void matchAB(const float* __restrict__ loc,
                                                  const float2* __restrict__ conf2,
                                                  const float4* __restrict__ priors,
                                                  const float* __restrict__ targets,
                                                  unsigned long long* __restrict__ bpm,
                                                  unsigned* __restrict__ cnt,
                                                  float* __restrict__ ce_mine,
                                                  int* __restrict__ num_pos,
                                                  float* __restrict__ loss_l_t,
                                                  float* __restrict__ ce_t,
                                                  int* __restrict__ np_tot) {
    int b = blockIdx.y;
    int base = blockIdx.x * BP;
    int tid = threadIdx.x;
    int lane = tid & 63, wv = tid >> 6;

    __shared__ float4 tb[On];
    __shared__ float  ta[On], lb[On];
    __shared__ int    forced[BP];    // truth index forcing this prior, else -1
    __shared__ float  sred[12];

#pragma unroll
    for (int j = 0; j < PPT; j++) forced[tid + 256 * j] = -1;
    if (tid < On) {
        const float* t = targets + ((size_t)b * On + tid) * 5;
        float x1 = t[0], y1 = t[1], x2 = t[2], y2 = t[3];
        tb[tid] = make_float4(x1, y1, x2, y2);
        ta[tid] = (x2 - x1) * (y2 - y1);
        lb[tid] = t[4];
    }
    __syncthreads();

    // ---------------- phase A: per-(b,o) argmax_p IoU ----------------
    // lane owns priors p = base + lane + 64*ig, ig in [0,16). Two halves
    // of 8 priors each, ig ascending across halves -> strict-> chain keeps
    // smallest p on product ties (identical semantics to r5/r7 phase A).
    {
        float bI[8], bU[8];
        int   bp[8];                 // absolute winning prior per target
#pragma unroll
        for (int t = 0; t < 8; t++) { bI[t] = 0.f; bU[t] = 1.f; bp[t] = base + lane; }

#pragma unroll
        for (int h = 0; h < 2; h++) {
            float ax1[8], ay1[8], ax2[8], ay2[8], aa[8];
#pragma unroll
            for (int i = 0; i < 8; i++) {
                float4 pr = priors[base + lane + 64 * (h * 8 + i)];
                ax1[i] = pr.x - pr.z * 0.5f; ay1[i] = pr.y - pr.w * 0.5f;
                ax2[i] = pr.x + pr.z * 0.5f; ay2[i] = pr.y + pr.w * 0.5f;
                aa[i]  = (ax2[i] - ax1[i]) * (ay2[i] - ay1[i]);
            }
#pragma unroll
            for (int t = 0; t < 8; t++) {
                int o = wv * 8 + t;
                float4 tt = tb[o];
                float  a  = ta[o];
#pragma unroll
                for (int i = 0; i < 8; i++) {
                    float ix1 = fmaxf(tt.x, ax1[i]), iy1 = fmaxf(tt.y, ay1[i]);
                    float ix2 = fminf(tt.z, ax2[i]), iy2 = fminf(tt.w, ay2[i]);
                    float iw = fmaxf(ix2 - ix1, 0.f), ih = fmaxf(iy2 - iy1, 0.f);
                    float I = iw * ih;
                    float U = a + aa[i] - I;
                    if (I * bU[t] > bI[t] * U) {
                        bI[t] = I; bU[t] = U; bp[t] = base + lane + 64 * (h * 8 + i);
                    }
                }
            }
        }

        unsigned long long key[8];
#pragma unroll
        for (int t = 0; t < 8; t++) {
            float iou = bI[t] / bU[t];       // IEEE divide: reference key rounding
            key[t] = ((unsigned long long)__float_as_uint(iou) << 32)
                   | (unsigned)(Pn - 1 - bp[t]);
        }
        // interleaved 6-level wave max-reduce of all 8 keys at once
#pragma unroll
        for (int off = 32; off > 0; off >>= 1) {
            unsigned long long other[8];
#pragma unroll
            for (int t = 0; t < 8; t++) other[t] = shfl_down_u64(key[t], off);
#pragma unroll
            for (int t = 0; t < 8; t++) if (other[t] > key[t]) key[t] = other[t];
        }
        if (lane == 0) {
#pragma unroll
            for (int t = 0; t < 8; t++)
                atomicMax(&bpm[b * On + wv * 8 + t], key[t]);
        }
    }

    // conf2 prefetch: HBM latency drains under barrier + spin
    float2 cc[PPT];
#pragma unroll
    for (int j = 0; j < PPT; j++) cc[j] = conf2[(size_t)b * Pn + base + tid + 256 * j];

    __syncthreads();            // vmcnt(0) drain: bpm atomics performed

    // per-batch ticket: wait for all NCHUNK sibling chunk-blocks.
    // RMW-only communication (device-scope atomics); polls proven cheap (r3).
    if (tid == 0) {
        atomicAdd(&cnt[b], 1u);
        while (atomicAdd(&cnt[b], 0u) < (unsigned)NCHUNK) {
            __builtin_amdgcn_s_sleep(16);
        }
    }
    __syncthreads();

    int sp = -1;
    if (tid < On)
        sp = Pn - 1 - (int)(atomicMax(&bpm[b * On + tid], 0ull) & 0xFFFFFFFFull);
    if (tid < On && sp >= base && sp < base + BP)
        atomicMax(&forced[sp - base], tid);   // duplicate bpi: max o == numpy last-write
    __syncthreads();

    // ---------------- phase B (verified matchB body) ----------------
    float px1[PPT], py1[PPT], px2[PPT], py2[PPT], ab[PPT], pcx[PPT], pcy[PPT], pw[PPT], ph[PPT];
#pragma unroll
    for (int j = 0; j < PPT; j++) {
        float4 pr = priors[base + tid + 256 * j];
        pcx[j] = pr.x; pcy[j] = pr.y; pw[j] = pr.z; ph[j] = pr.w;
        px1[j] = pr.x - pr.z * 0.5f; py1[j] = pr.y - pr.w * 0.5f;
        px2[j] = pr.x + pr.z * 0.5f; py2[j] = pr.y + pr.w * 0.5f;
        ab[j]  = (px2[j] - px1[j]) * (py2[j] - py1[j]);
    }

    // two independent 16-long chains per prior (h = o/16), merged after.
    float bIc[PPT][2], bUc[PPT][2];
    int   bxc[PPT][2];
#pragma unroll
    for (int j = 0; j < PPT; j++)
#pragma unroll
        for (int h = 0; h < 2; h++) { bIc[j][h] = 0.f; bUc[j][h] = 1.f; bxc[j][h] = h * 16; }

#pragma unroll 2
    for (int o16 = 0; o16 < 16; o16++) {
#pragma unroll
        for (int h = 0; h < 2; h++) {
            int o = h * 16 + o16;
            float4 tt = tb[o];
            float  a  = ta[o];
#pragma unroll
            for (int j = 0; j < PPT; j++) {
                float ix1 = fmaxf(tt.x, px1[j]), iy1 = fmaxf(tt.y, py1[j]);
                float ix2 = fminf(tt.z, px2[j]), iy2 = fminf(tt.w, py2[j]);
                float iw = fmaxf(ix2 - ix1, 0.f), ih = fmaxf(iy2 - iy1, 0.f);
                float I = iw * ih;
                float U = a + ab[j] - I;
                if (I * bUc[j][h] > bIc[j][h] * U) { bIc[j][h] = I; bUc[j][h] = U; bxc[j][h] = o; }
            }
        }
    }
    // merge: chain1 wins only if strictly greater -> earliest-o tie semantics kept
    float bI[PPT], bU[PPT];
    int   bx[PPT];
#pragma unroll
    for (int j = 0; j < PPT; j++) {
        bI[j] = bIc[j][0]; bU[j] = bUc[j][0]; bx[j] = bxc[j][0];
        if (bIc[j][1] * bU[j] > bI[j] * bUc[j][1]) { bI[j] = bIc[j][1]; bU[j] = bUc[j][1]; bx[j] = bxc[j][1]; }
    }

    float ll_s = 0.f, pce_s = 0.f, cnt_s = 0.f;
#pragma unroll
    for (int j = 0; j < PPT; j++) {
        int p = base + tid + 256 * j;
        int fo = forced[tid + 256 * j];
        int bidx = (fo >= 0) ? fo : bx[j];
        int cf;
        if (fo >= 0)                      cf = (int)lb[bidx];
        else if (bI[j] >= 0.5f * bU[j])   cf = (int)lb[bidx];
        else                              cf = 0;
        bool pos = cf > 0;

        if (pos) {
            float4 tt = tb[bidx];
            float g0 = ((tt.x + tt.z) * 0.5f - pcx[j]) / (0.1f * pw[j]);
            float g1 = ((tt.y + tt.w) * 0.5f - pcy[j]) / (0.1f * ph[j]);
            float g2 = __logf((tt.z - tt.x) / pw[j]) * 5.0f;
            float g3 = __logf((tt.w - tt.y) / ph[j]) * 5.0f;
            const float* lp = loc + ((size_t)b * Pn + p) * 3;
            float q0 = lp[0], q1 = lp[1], q2 = lp[2];
            float dd[4] = { q0 - g0, q1 - g1, q2 - g2, q2 - g3 };
#pragma unroll
            for (int i = 0; i < 4; i++) {
                float ad = fabsf(dd[i]);
                ll_s += (ad < 1.f) ? 0.5f * dd[i] * dd[i] : (ad - 0.5f);
            }
            cnt_s += 1.f;
        }

        float m = fmaxf(cc[j].x, cc[j].y);
        float lse = m + __logf(__expf(cc[j].x - m) + __expf(cc[j].y - m));
        float ce = lse - (cf ? cc[j].y : cc[j].x);     // >= 0
        if (pos) { pce_s += ce; ce = 0.f; }
        ce_mine[(size_t)b * Pn + p] = fmaxf(ce, 0.f);
    }

    // fused 3-value block reduce
#pragma unroll
    for (int off = 32; off > 0; off >>= 1) {
        ll_s  += __shfl_down(ll_s,  off, 64);
        pce_s += __shfl_down(pce_s, off, 64);
        cnt_s += __shfl_down(cnt_s, off, 64);
    }
    if (lane == 0) { sred[wv * 3] = ll_s; sred[wv * 3 + 1] = pce_s; sred[wv * 3 + 2] = cnt_s; }
    __syncthreads();
    if (tid == 0) {
        float llr = 0, pcer = 0, cntr = 0;
        for (int w = 0; w < 4; w++) { llr += sred[w*3]; pcer += sred[w*3+1]; cntr += sred[w*3+2]; }
        if (llr != 0.f)  atomicAdd(loss_l_t, llr);
        if (pcer != 0.f) atomicAdd(ce_t, pcer);
        int c = (int)cntr;
        if (c) { atomicAdd(&num_pos[b], c); atomicAdd(np_tot, c); }
    }
}

// ---- Phase C: exact top-k sum via 3-round radix histogram select ----
// (unchanged control)
__global__ __launch_bounds__(1024) void topk(const float* __restrict__ ce_mine,
                                             const int* __restrict__ num_pos,
                                             float* __restrict__ ce_t,
                                             const float* __restrict__ loss_l_t,
                                             const int* __restrict__ np_tot,
                                             unsigned* __restrict__ tick,
                                             float* __restrict__ out) {
    int b = blockIdx.x, tid = threadIdx.x;
    const float4* v4 = (const float4*)(ce_mine + (size_t)b * Pn);
    float4 r[8];
#pragma unroll
    for (int i = 0; i < 8; i++) r[i] = v4[i * 1024 + tid];

    int k = 3 * num_pos[b];
    if (k > Pn - 1) k = Pn - 1;

    __shared__ int hist[8192];                // 4 sub-hists x 2048 bins (32KB)
    __shared__ unsigned s_lo;
    __shared__ int s_ab;
    __shared__ float ssum[16];
    __shared__ int   scnt[16];

    int lane = tid & 63, wv = tid >> 6;

    if (k > 0) {                              // uniform across block
        unsigned LO = 0u;
        int AB = 0;                           // count(u >= bracket top)

        const int SH[3] = {22, 11, 0};
        const int NB[3] = {512, 2048, 2048};

#pragma unroll
        for (int rd = 0; rd < 3; rd++) {
            int shift = SH[rd], nb = NB[rd];
#pragma unroll
            for (int i = 0; i < 8; i++) hist[tid + 1024 * i] = 0;
            __syncthreads();
            int* myh = hist + ((wv >> 2) << 11);   // 4-way sub-hist
#pragma unroll
            for (int i = 0; i < 8; i++) {
                float4 rv = r[i];
                float vals[4] = {rv.x, rv.y, rv.z, rv.w};
#pragma unroll
                for (int q = 0; q < 4; q++) {
                    unsigned u = __float_as_uint(vals[q]);
                    unsigned bin = (u - LO) >> shift;        // underflow -> huge -> skipped
                    if (bin < (unsigned)nb) atomicAdd(&myh[bin], 1);
                }
            }
            __syncthreads();
            if (wv == 0) {
                int bpl = nb >> 6;            // bins per lane: 8 or 32
                int bb = lane * bpl;
                int lsum = 0;
                for (int q = 0; q < bpl; q++) {
                    int bin = bb + q;
                    lsum += hist[bin] + hist[2048 + bin] + hist[4096 + bin] + hist[6144 + bin];
                }
                // inclusive suffix-scan over lanes: suf = count(bins >= bb)
                int suf = lsum;
#pragma unroll
                for (int off = 1; off < 64; off <<= 1) {
                    int o = __shfl(suf, (lane + off) & 63, 64);
                    suf += ((lane + off) < 64) ? o : 0;
                }
                int kk = k - AB;              // >= 1 by invariant
                if (suf >= kk && (suf - lsum) < kk) {   // crossing lane (unique)
                    int acc = suf - lsum;     // count(bins >= bb+bpl)
                    for (int q = bpl - 1; q >= 0; q--) {
                        int bin = bb + q;
                        int hc = hist[bin] + hist[2048 + bin] + hist[4096 + bin] + hist[6144 + bin];
                        acc += hc;            // = count(bins >= bb+q)
                        if (acc >= kk) {
                            s_lo = LO + ((unsigned)bin << shift);
                            s_ab = AB + (acc - hc);
                            break;
                        }
                    }
                }
            }
            __syncthreads();
            LO = s_lo; AB = s_ab;
        }
        // final bracket width 1: tau bits == LO; count(> tau) = AB < k <= count(>= tau)
        float tau = __uint_as_float(LO);
        float s = 0.f; int c = 0;
#pragma unroll
        for (int i = 0; i < 8; i++) {
            if (r[i].x > tau) { s += r[i].x; c++; }
            if (r[i].y > tau) { s += r[i].y; c++; }
            if (r[i].z > tau) { s += r[i].z; c++; }
            if (r[i].w > tau) { s += r[i].w; c++; }
        }
#pragma unroll
        for (int off = 32; off > 0; off >>= 1) {
            s += __shfl_down(s, off, 64);
            c += __shfl_down(c, off, 64);
        }
        if (lane == 0) { ssum[wv] = s; scnt[wv] = c; }
        __syncthreads();
        if (tid == 0) {
            float st = 0.f; int ct = 0;
            for (int w = 0; w < 16; w++) { st += ssum[w]; ct += scnt[w]; }
            atomicAdd(ce_t, st + (float)(k - ct) * tau);   // ties at tau, tie-agnostic exact
        }
    }

    // ticket: last block finalizes (device-scope atomics; adds happen-before ticket)
    if (tid == 0) {
        __threadfence();
        unsigned done = atomicAdd(tick, 1u);
        if (done == (unsigned)(Bn - 1)) {
            float N  = (float)atomicAdd((int*)np_tot, 0);
            float ll = atomicAdd((float*)loss_l_t, 0.f);
            float ce = atomicAdd(ce_t, 0.f);
            out[0] = ll / N;
            out[1] = ce / N;
        }
    }
}

extern "C" void kernel_launch(void* const* d_in, const int* in_sizes, int n_in,
                              void* d_out, int out_size, void* d_ws, size_t ws_size,
                              hipStream_t stream) {
    const float* loc     = (const float*)d_in[0];  // (B,P,3)
    const float* conf    = (const float*)d_in[1];  // (B,P,2)
    const float* priors  = (const float*)d_in[2];  // (P,4)
    const float* targets = (const float*)d_in[3];  // (B,O,5)
    float* out = (float*)d_out;

    char* ws = (char*)d_ws;
    unsigned long long* bpm = (unsigned long long*)ws;
    int*   num_pos  = (int*)(ws + 8192);
    float* loss_l_t = (float*)(ws + 8320);
    float* ce_t     = (float*)(ws + 8324);
    int*   np_tot   = (int*)(ws + 8328);
    unsigned* tick  = (unsigned*)(ws + 8332);
    unsigned* cnt   = (unsigned*)(ws + 8336);
    float* ce_mine  = (float*)(ws + 16384);

    hipMemsetAsync(ws, 0, 16384, stream);

    hipLaunchKernelGGL(matchAB, dim3(NCHUNK, Bn), dim3(256), 0, stream,
                       loc, (const float2*)conf, (const float4*)priors, targets,
                       bpm, cnt, ce_mine, num_pos, loss_l_t, ce_t, np_tot);
    hipLaunchKernelGGL(topk, dim3(Bn), dim3(1024), 0, stream,
                       ce_mine, num_pos, ce_t, loss_l_t, np_tot, tick, out);
}

// Round 9
// 158.611 us; speedup vs baseline: 2.4859x; 1.1840x over previous
//
#include <hip/hip_runtime.h>
#include <math.h>

#define Bn 32
#define Pn 32768
#define On 32
#define TPB 256
#define PPT 4                 // priors per thread in B-role
#define BP  (TPB * PPT)       // priors per block = 1024
#define NCHUNK (Pn / BP)      // 32 chunk-blocks per batch

// d_ws layout:
// [0,     8192)  u64   bpm[Bn*On]   packed (iou_bits<<32 | (Pn-1-p)) per (b,o)
// [8192,  8320)  int   num_pos[Bn]
// [8320,  8324)  float loss_l_total
// [8324,  8328)  float ce_total
// [8328,  8332)  int   np_total
// [8332,  8336)  uint  tick (topk completion ticket)
// [16384, 16384+4*Bn*Pn) float ce_mine[Bn*Pn]

__device__ __forceinline__ unsigned long long shfl_down_u64(unsigned long long v, int off) {
    unsigned lo = (unsigned)(v & 0xFFFFFFFFull);
    unsigned hi = (unsigned)(v >> 32);
    lo = __shfl_down(lo, off, 64);
    hi = __shfl_down(hi, off, 64);
    return ((unsigned long long)hi << 32) | lo;
}

// ---- match: A-role and B-role as INDEPENDENT blocks of one dispatch ----
// grid (NCHUNK, Bn, 2): z==0 -> A-role (per-o argmax -> bpm, r8 two-half
// no-spill structure); z==1 -> B-role (per-prior matching WITHOUT forced
// correction -- the <=32 forced priors/batch are fixed up in topk's
// prologue). No spin, no cross-block dependency; A's latency-bound waves
// co-schedule with B's VALU-bound waves on the same CUs.
__global__ __launch_bounds__(256) void match(const float* __restrict__ loc,
                                             const float2* __restrict__ conf2,
                                             const float4* __restrict__ priors,
                                             const float* __restrict__ targets,
                                             unsigned long long* __restrict__ bpm,
                                             float* __restrict__ ce_mine,
                                             int* __restrict__ num_pos,
                                             float* __restrict__ loss_l_t,
                                             float* __restrict__ ce_t,
                                             int* __restrict__ np_tot) {
    int b = blockIdx.y;
    int base = blockIdx.x * BP;
    int tid = threadIdx.x;
    int lane = tid & 63, wv = tid >> 6;

    __shared__ float4 tb[On];
    __shared__ float  ta[On], lb[On];
    __shared__ float  sred[12];

    if (tid < On) {
        const float* t = targets + ((size_t)b * On + tid) * 5;
        float x1 = t[0], y1 = t[1], x2 = t[2], y2 = t[3];
        tb[tid] = make_float4(x1, y1, x2, y2);
        ta[tid] = (x2 - x1) * (y2 - y1);
        lb[tid] = t[4];
    }
    __syncthreads();

    if (blockIdx.z == 0) {
        // ---------------- A-role: per-(b,o) argmax_p IoU ----------------
        // lane owns priors p = base + lane + 64*ig, two halves of 8 (no
        // spill); wave wv covers targets wv*8..wv*8+7 over all 1024 priors.
        float bI[8], bU[8];
        int   bp[8];
#pragma unroll
        for (int t = 0; t < 8; t++) { bI[t] = 0.f; bU[t] = 1.f; bp[t] = base + lane; }

#pragma unroll
        for (int h = 0; h < 2; h++) {
            float ax1[8], ay1[8], ax2[8], ay2[8], aa[8];
#pragma unroll
            for (int i = 0; i < 8; i++) {
                float4 pr = priors[base + lane + 64 * (h * 8 + i)];
                ax1[i] = pr.x - pr.z * 0.5f; ay1[i] = pr.y - pr.w * 0.5f;
                ax2[i] = pr.x + pr.z * 0.5f; ay2[i] = pr.y + pr.w * 0.5f;
                aa[i]  = (ax2[i] - ax1[i]) * (ay2[i] - ay1[i]);
            }
#pragma unroll
            for (int t = 0; t < 8; t++) {
                int o = wv * 8 + t;
                float4 tt = tb[o];
                float  a  = ta[o];
#pragma unroll
                for (int i = 0; i < 8; i++) {
                    float ix1 = fmaxf(tt.x, ax1[i]), iy1 = fmaxf(tt.y, ay1[i]);
                    float ix2 = fminf(tt.z, ax2[i]), iy2 = fminf(tt.w, ay2[i]);
                    float iw = fmaxf(ix2 - ix1, 0.f), ih = fmaxf(iy2 - iy1, 0.f);
                    float I = iw * ih;
                    float U = a + aa[i] - I;
                    if (I * bU[t] > bI[t] * U) {
                        bI[t] = I; bU[t] = U; bp[t] = base + lane + 64 * (h * 8 + i);
                    }
                }
            }
        }
        unsigned long long key[8];
#pragma unroll
        for (int t = 0; t < 8; t++) {
            float iou = bI[t] / bU[t];       // IEEE divide: reference key rounding
            key[t] = ((unsigned long long)__float_as_uint(iou) << 32)
                   | (unsigned)(Pn - 1 - bp[t]);
        }
#pragma unroll
        for (int off = 32; off > 0; off >>= 1) {
            unsigned long long other[8];
#pragma unroll
            for (int t = 0; t < 8; t++) other[t] = shfl_down_u64(key[t], off);
#pragma unroll
            for (int t = 0; t < 8; t++) if (other[t] > key[t]) key[t] = other[t];
        }
        if (lane == 0) {
#pragma unroll
            for (int t = 0; t < 8; t++)
                atomicMax(&bpm[b * On + wv * 8 + t], key[t]);
        }
        return;
    }

    // ---------------- B-role (verified matchB body, forced[] removed) ----
    float2 cc[PPT];
#pragma unroll
    for (int j = 0; j < PPT; j++) cc[j] = conf2[(size_t)b * Pn + base + tid + 256 * j];

    float px1[PPT], py1[PPT], px2[PPT], py2[PPT], ab[PPT], pcx[PPT], pcy[PPT], pw[PPT], ph[PPT];
#pragma unroll
    for (int j = 0; j < PPT; j++) {
        float4 pr = priors[base + tid + 256 * j];
        pcx[j] = pr.x; pcy[j] = pr.y; pw[j] = pr.z; ph[j] = pr.w;
        px1[j] = pr.x - pr.z * 0.5f; py1[j] = pr.y - pr.w * 0.5f;
        px2[j] = pr.x + pr.z * 0.5f; py2[j] = pr.y + pr.w * 0.5f;
        ab[j]  = (px2[j] - px1[j]) * (py2[j] - py1[j]);
    }

    // two independent 16-long chains per prior (h = o/16), merged after.
    float bIc[PPT][2], bUc[PPT][2];
    int   bxc[PPT][2];
#pragma unroll
    for (int j = 0; j < PPT; j++)
#pragma unroll
        for (int h = 0; h < 2; h++) { bIc[j][h] = 0.f; bUc[j][h] = 1.f; bxc[j][h] = h * 16; }

#pragma unroll 2
    for (int o16 = 0; o16 < 16; o16++) {
#pragma unroll
        for (int h = 0; h < 2; h++) {
            int o = h * 16 + o16;
            float4 tt = tb[o];
            float  a  = ta[o];
#pragma unroll
            for (int j = 0; j < PPT; j++) {
                float ix1 = fmaxf(tt.x, px1[j]), iy1 = fmaxf(tt.y, py1[j]);
                float ix2 = fminf(tt.z, px2[j]), iy2 = fminf(tt.w, py2[j]);
                float iw = fmaxf(ix2 - ix1, 0.f), ih = fmaxf(iy2 - iy1, 0.f);
                float I = iw * ih;
                float U = a + ab[j] - I;
                if (I * bUc[j][h] > bIc[j][h] * U) { bIc[j][h] = I; bUc[j][h] = U; bxc[j][h] = o; }
            }
        }
    }
    float bI[PPT], bU[PPT];
    int   bx[PPT];
#pragma unroll
    for (int j = 0; j < PPT; j++) {
        bI[j] = bIc[j][0]; bU[j] = bUc[j][0]; bx[j] = bxc[j][0];
        if (bIc[j][1] * bU[j] > bI[j] * bUc[j][1]) { bI[j] = bIc[j][1]; bU[j] = bUc[j][1]; bx[j] = bxc[j][1]; }
    }

    float ll_s = 0.f, pce_s = 0.f, cnt_s = 0.f;
#pragma unroll
    for (int j = 0; j < PPT; j++) {
        int p = base + tid + 256 * j;
        int bidx = bx[j];
        int cf = (bI[j] >= 0.5f * bU[j]) ? (int)lb[bidx] : 0;
        bool pos = cf > 0;

        if (pos) {
            float4 tt = tb[bidx];
            float g0 = ((tt.x + tt.z) * 0.5f - pcx[j]) / (0.1f * pw[j]);
            float g1 = ((tt.y + tt.w) * 0.5f - pcy[j]) / (0.1f * ph[j]);
            float g2 = __logf((tt.z - tt.x) / pw[j]) * 5.0f;
            float g3 = __logf((tt.w - tt.y) / ph[j]) * 5.0f;
            const float* lp = loc + ((size_t)b * Pn + p) * 3;
            float q0 = lp[0], q1 = lp[1], q2 = lp[2];
            float dd[4] = { q0 - g0, q1 - g1, q2 - g2, q2 - g3 };
#pragma unroll
            for (int i = 0; i < 4; i++) {
                float ad = fabsf(dd[i]);
                ll_s += (ad < 1.f) ? 0.5f * dd[i] * dd[i] : (ad - 0.5f);
            }
            cnt_s += 1.f;
        }

        float m = fmaxf(cc[j].x, cc[j].y);
        float lse = m + __logf(__expf(cc[j].x - m) + __expf(cc[j].y - m));
        float ce = lse - (cf ? cc[j].y : cc[j].x);     // >= 0
        if (pos) { pce_s += ce; ce = 0.f; }
        ce_mine[(size_t)b * Pn + p] = fmaxf(ce, 0.f);
    }

#pragma unroll
    for (int off = 32; off > 0; off >>= 1) {
        ll_s  += __shfl_down(ll_s,  off, 64);
        pce_s += __shfl_down(pce_s, off, 64);
        cnt_s += __shfl_down(cnt_s, off, 64);
    }
    if (lane == 0) { sred[wv * 3] = ll_s; sred[wv * 3 + 1] = pce_s; sred[wv * 3 + 2] = cnt_s; }
    __syncthreads();
    if (tid == 0) {
        float llr = 0, pcer = 0, cntr = 0;
        for (int w = 0; w < 4; w++) { llr += sred[w*3]; pcer += sred[w*3+1]; cntr += sred[w*3+2]; }
        if (llr != 0.f)  atomicAdd(loss_l_t, llr);
        if (pcer != 0.f) atomicAdd(ce_t, pcer);
        int c = (int)cntr;
        if (c) { atomicAdd(&num_pos[b], c); atomicAdd(np_tot, c); }
    }
}

// ---- topk: forced-prior fixup prologue + 3-round radix select ----
// Fixup (lanes 0..31): resolve duplicate forced priors (max o = numpy
// last-write), recompute the EXACT matchB arithmetic for each forced
// prior (verbatim op sequence -> identical floats), apply atomic deltas
// to loss_l/ce_t/num_pos and rewrite ce_mine[p] BEFORE selection loads.
// Then the r5 collapsed-histogram select. Last block finalizes.
__global__ __launch_bounds__(1024) void topk(const float* __restrict__ loc,
                                             const float2* __restrict__ conf2,
                                             const float4* __restrict__ priors,
                                             const float* __restrict__ targets,
                                             const unsigned long long* __restrict__ bpm,
                                             float* __restrict__ ce_mine,
                                             int* __restrict__ num_pos,
                                             float* __restrict__ ce_t,
                                             float* __restrict__ loss_l_t,
                                             int* __restrict__ np_tot,
                                             unsigned* __restrict__ tick,
                                             float* __restrict__ out) {
    int b = blockIdx.x, tid = threadIdx.x;
    int lane = tid & 63, wv = tid >> 6;

    __shared__ int hist[8192];                // 4 sub-hists x 2048 bins (32KB)
    __shared__ float4 ftb[On];
    __shared__ float  fta[On], flb[On];
    __shared__ int    fpr[On];
    __shared__ int    s_k;
    __shared__ unsigned s_lo;
    __shared__ int s_ab;
    __shared__ float ssum[16];
    __shared__ int   scnt[16];

    // ---------------- fixup prologue ----------------
    if (tid < On) {
        const float* t = targets + ((size_t)b * On + tid) * 5;
        float x1 = t[0], y1 = t[1], x2 = t[2], y2 = t[3];
        ftb[tid] = make_float4(x1, y1, x2, y2);
        fta[tid] = (x2 - x1) * (y2 - y1);
        flb[tid] = t[4];
        fpr[tid] = Pn - 1 - (int)(bpm[b * On + tid] & 0xFFFFFFFFull);
    }
    __syncthreads();
    if (tid < On) {
        int pt = fpr[tid];
        bool winner = true;                   // max-o wins among duplicates
        for (int t2 = tid + 1; t2 < On; t2++) if (fpr[t2] == pt) winner = false;
        if (winner) {
            float4 pr = priors[pt];
            float pcx = pr.x, pcy = pr.y, pw = pr.z, ph = pr.w;
            float px1 = pr.x - pr.z * 0.5f, py1 = pr.y - pr.w * 0.5f;
            float px2 = pr.x + pr.z * 0.5f, py2 = pr.y + pr.w * 0.5f;
            float ab  = (px2 - px1) * (py2 - py1);
            // replicate matchB's two-half chain EXACTLY
            float bIc[2] = {0.f, 0.f}, bUc[2] = {1.f, 1.f};
            int   bxc[2] = {0, 16};
            for (int o16 = 0; o16 < 16; o16++) {
                for (int h = 0; h < 2; h++) {
                    int o = h * 16 + o16;
                    float4 tt = ftb[o];
                    float  a  = fta[o];
                    float ix1 = fmaxf(tt.x, px1), iy1 = fmaxf(tt.y, py1);
                    float ix2 = fminf(tt.z, px2), iy2 = fminf(tt.w, py2);
                    float iw = fmaxf(ix2 - ix1, 0.f), ih = fmaxf(iy2 - iy1, 0.f);
                    float I = iw * ih;
                    float U = a + ab - I;
                    if (I * bUc[h] > bIc[h] * U) { bIc[h] = I; bUc[h] = U; bxc[h] = o; }
                }
            }
            float bI = bIc[0], bU = bUc[0]; int bx = bxc[0];
            if (bIc[1] * bU > bI * bUc[1]) { bI = bIc[1]; bU = bUc[1]; bx = bxc[1]; }

            int  cf_old  = (bI >= 0.5f * bU) ? (int)flb[bx] : 0;
            bool pos_old = cf_old > 0;
            int  cf_new  = (int)flb[tid];
            bool pos_new = cf_new > 0;

            float2 cc = conf2[(size_t)b * Pn + pt];
            float m = fmaxf(cc.x, cc.y);
            float lse = m + __logf(__expf(cc.x - m) + __expf(cc.y - m));
            float ce_old = lse - (cf_old ? cc.y : cc.x);
            float ce_new = lse - (cf_new ? cc.y : cc.x);

            const float* lp = loc + ((size_t)b * Pn + pt) * 3;
            float q0 = lp[0], q1 = lp[1], q2 = lp[2];
            float ll_old = 0.f, ll_new = 0.f;
            if (pos_old) {
                float4 tt = ftb[bx];
                float g0 = ((tt.x + tt.z) * 0.5f - pcx) / (0.1f * pw);
                float g1 = ((tt.y + tt.w) * 0.5f - pcy) / (0.1f * ph);
                float g2 = __logf((tt.z - tt.x) / pw) * 5.0f;
                float g3 = __logf((tt.w - tt.y) / ph) * 5.0f;
                float dd[4] = { q0 - g0, q1 - g1, q2 - g2, q2 - g3 };
                for (int i = 0; i < 4; i++) {
                    float ad = fabsf(dd[i]);
                    ll_old += (ad < 1.f) ? 0.5f * dd[i] * dd[i] : (ad - 0.5f);
                }
            }
            if (pos_new) {
                float4 tt = ftb[tid];
                float g0 = ((tt.x + tt.z) * 0.5f - pcx) / (0.1f * pw);
                float g1 = ((tt.y + tt.w) * 0.5f - pcy) / (0.1f * ph);
                float g2 = __logf((tt.z - tt.x) / pw) * 5.0f;
                float g3 = __logf((tt.w - tt.y) / ph) * 5.0f;
                float dd[4] = { q0 - g0, q1 - g1, q2 - g2, q2 - g3 };
                for (int i = 0; i < 4; i++) {
                    float ad = fabsf(dd[i]);
                    ll_new += (ad < 1.f) ? 0.5f * dd[i] * dd[i] : (ad - 0.5f);
                }
            }
            float dll = ll_new - ll_old;
            float dce = (pos_new ? ce_new : 0.f) - (pos_old ? ce_old : 0.f);
            int   dnp = (pos_new ? 1 : 0) - (pos_old ? 1 : 0);
            if (dll != 0.f) atomicAdd(loss_l_t, dll);
            if (dce != 0.f) atomicAdd(ce_t, dce);
            if (dnp) { atomicAdd(&num_pos[b], dnp); atomicAdd(np_tot, dnp); }
            float cm_new = pos_new ? 0.f : fmaxf(ce_new, 0.f);
            ce_mine[(size_t)b * Pn + pt] = cm_new;
        }
    }
    if (tid == 0) s_k = atomicAdd(&num_pos[b], 0);   // L2-fresh read
    __syncthreads();

    // ---------------- selection (r5 collapsed histogram) ----------------
    const float4* v4 = (const float4*)(ce_mine + (size_t)b * Pn);
    float4 r[8];
#pragma unroll
    for (int i = 0; i < 8; i++) r[i] = v4[i * 1024 + tid];

    int k = 3 * s_k;
    if (k > Pn - 1) k = Pn - 1;

    if (k > 0) {                              // uniform across block
        unsigned LO = 0u;
        int AB = 0;                           // count(u >= bracket top)

        const int SH[3] = {22, 11, 0};
        const int NB[3] = {512, 2048, 2048};

#pragma unroll
        for (int rd = 0; rd < 3; rd++) {
            int shift = SH[rd], nb = NB[rd];
#pragma unroll
            for (int i = 0; i < 8; i++) hist[tid + 1024 * i] = 0;
            __syncthreads();
            int* myh = hist + ((wv >> 2) << 11);   // 4-way sub-hist
#pragma unroll
            for (int i = 0; i < 8; i++) {
                float4 rv = r[i];
                float vals[4] = {rv.x, rv.y, rv.z, rv.w};
#pragma unroll
                for (int q = 0; q < 4; q++) {
                    unsigned u = __float_as_uint(vals[q]);
                    unsigned bin = (u - LO) >> shift;        // underflow -> huge -> skipped
                    if (bin < (unsigned)nb) atomicAdd(&myh[bin], 1);
                }
            }
            __syncthreads();
            if (wv == 0) {
                int bpl = nb >> 6;            // bins per lane: 8 or 32
                int bb = lane * bpl;
                int lsum = 0;
                for (int q = 0; q < bpl; q++) {
                    int bin = bb + q;
                    lsum += hist[bin] + hist[2048 + bin] + hist[4096 + bin] + hist[6144 + bin];
                }
                int suf = lsum;
#pragma unroll
                for (int off = 1; off < 64; off <<= 1) {
                    int o = __shfl(suf, (lane + off) & 63, 64);
                    suf += ((lane + off) < 64) ? o : 0;
                }
                int kk = k - AB;              // >= 1 by invariant
                if (suf >= kk && (suf - lsum) < kk) {   // crossing lane (unique)
                    int acc = suf - lsum;
                    for (int q = bpl - 1; q >= 0; q--) {
                        int bin = bb + q;
                        int hc = hist[bin] + hist[2048 + bin] + hist[4096 + bin] + hist[6144 + bin];
                        acc += hc;
                        if (acc >= kk) {
                            s_lo = LO + ((unsigned)bin << shift);
                            s_ab = AB + (acc - hc);
                            break;
                        }
                    }
                }
            }
            __syncthreads();
            LO = s_lo; AB = s_ab;
        }
        float tau = __uint_as_float(LO);
        float s = 0.f; int c = 0;
#pragma unroll
        for (int i = 0; i < 8; i++) {
            if (r[i].x > tau) { s += r[i].x; c++; }
            if (r[i].y > tau) { s += r[i].y; c++; }
            if (r[i].z > tau) { s += r[i].z; c++; }
            if (r[i].w > tau) { s += r[i].w; c++; }
        }
#pragma unroll
        for (int off = 32; off > 0; off >>= 1) {
            s += __shfl_down(s, off, 64);
            c += __shfl_down(c, off, 64);
        }
        if (lane == 0) { ssum[wv] = s; scnt[wv] = c; }
        __syncthreads();
        if (tid == 0) {
            float st = 0.f; int ct = 0;
            for (int w = 0; w < 16; w++) { st += ssum[w]; ct += scnt[w]; }
            atomicAdd(ce_t, st + (float)(k - ct) * tau);   // ties at tau, tie-agnostic exact
        }
    }

    // ticket: last block finalizes
    if (tid == 0) {
        __threadfence();
        unsigned done = atomicAdd(tick, 1u);
        if (done == (unsigned)(Bn - 1)) {
            float N  = (float)atomicAdd(np_tot, 0);
            float ll = atomicAdd(loss_l_t, 0.f);
            float ce = atomicAdd(ce_t, 0.f);
            out[0] = ll / N;
            out[1] = ce / N;
        }
    }
}

extern "C" void kernel_launch(void* const* d_in, const int* in_sizes, int n_in,
                              void* d_out, int out_size, void* d_ws, size_t ws_size,
                              hipStream_t stream) {
    const float* loc     = (const float*)d_in[0];  // (B,P,3)
    const float* conf    = (const float*)d_in[1];  // (B,P,2)
    const float* priors  = (const float*)d_in[2];  // (P,4)
    const float* targets = (const float*)d_in[3];  // (B,O,5)
    float* out = (float*)d_out;

    char* ws = (char*)d_ws;
    unsigned long long* bpm = (unsigned long long*)ws;
    int*   num_pos  = (int*)(ws + 8192);
    float* loss_l_t = (float*)(ws + 8320);
    float* ce_t     = (float*)(ws + 8324);
    int*   np_tot   = (int*)(ws + 8328);
    unsigned* tick  = (unsigned*)(ws + 8332);
    float* ce_mine  = (float*)(ws + 16384);

    hipMemsetAsync(ws, 0, 16384, stream);

    hipLaunchKernelGGL(match, dim3(NCHUNK, Bn, 2), dim3(256), 0, stream,
                       loc, (const float2*)conf, (const float4*)priors, targets,
                       bpm, ce_mine, num_pos, loss_l_t, ce_t, np_tot);
    hipLaunchKernelGGL(topk, dim3(Bn), dim3(1024), 0, stream,
                       loc, (const float2*)conf, (const float4*)priors, targets, bpm,
                       ce_mine, num_pos, ce_t, loss_l_t, np_tot, tick, out);
}